// Round 5
// baseline (19051.488 us; speedup 1.0000x reference)
//
#include <hip/hip_runtime.h>
#include <math.h>
#include <limits.h>

#define BB 64
#define SS 400
#define HH 256
#define EE 128
#define VV 50000
#define VEXTT 50100
#define NSTEPS 32
#define NBK 256      // B*K beams
#define NCH 196      // ceil(50000/256) vocab chunks of 256
#define VCH 256      // columns per chunk
#define NSLOT 596    // SS + NCH candidate slots per beam
#define NBMW 1568    // bitmap words per batch (50100 bits)

__device__ __forceinline__ float sigf(float x){ return 1.0f/(1.0f+expf(-x)); }
__device__ __forceinline__ bool betterf(float v, int key, float v2, int key2){
  return v > v2 || (v == v2 && key < key2);
}

// ---------------- init state ----------------
__global__ void k_init(const float* __restrict__ h0, const float* __restrict__ c0,
                       float* hS, float* cS, float* ctxS, float* logp, int* tok, int* tokens){
  int bk = blockIdx.x; int b = bk >> 2; int t = threadIdx.x;
  hS[bk*HH+t] = h0[b*HH+t];
  cS[bk*HH+t] = c0[b*HH+t];
  ctxS[bk*HH+t] = 0.f;
  if(t==0){ logp[bk] = ((bk&3)==0) ? 0.f : -1e9f; tok[bk] = 2; }
  if(t < NSTEPS) tokens[bk*NSTEPS + t] = 0;
}

// ---------------- enc_feats = enc_outputs @ W_enc ----------------
#define TSR 16
__global__ __launch_bounds__(256) void k_encfeats(const float* __restrict__ enc,
                                                  const float* __restrict__ W,
                                                  float* __restrict__ ef){
  int blk = blockIdx.x;               // 64 * 25
  int b = blk/25, s0 = (blk%25)*TSR;
  int t = threadIdx.x;
  __shared__ float rows[TSR*HH];
  for(int i=t;i<TSR*HH;i+=256) rows[i] = enc[((size_t)b*SS + s0)*HH + i];
  __syncthreads();
  float a[TSR];
  #pragma unroll
  for(int r=0;r<TSR;++r) a[r]=0.f;
  for(int h=0;h<HH;++h){
    float w = W[h*HH + t];
    #pragma unroll
    for(int r=0;r<TSR;++r) a[r] += rows[r*HH + h]*w;
  }
  for(int r=0;r<TSR;++r) ef[((size_t)b*SS + s0 + r)*HH + t] = a[r];
}

// ---------------- one-time: dup structure + copy-id bitmap ----------------
__global__ __launch_bounds__(256) void k_prep(const int* __restrict__ ids,
                                              int* __restrict__ nexts, int* __restrict__ firstS,
                                              unsigned* __restrict__ bmC){
  int b = blockIdx.x; int t = threadIdx.x;
  __shared__ int sI[SS];
  for(int i=t;i<SS;i+=256) sI[i]=ids[(size_t)b*SS+i];
  for(int i=t;i<NBMW;i+=256) bmC[(size_t)b*NBMW+i]=0u;
  __syncthreads();
  for(int s=t; s<SS; s+=256){
    int id=sI[s]; int fo=1, nx=-1;
    for(int s2=0;s2<s;++s2) if(sI[s2]==id){fo=0;break;}
    for(int s2=s+1;s2<SS;++s2) if(sI[s2]==id){nx=s2;break;}
    firstS[(size_t)b*SS+s]=fo; nexts[(size_t)b*SS+s]=nx;
    if(fo && id<VV) atomicOr(&bmC[(size_t)b*NBMW + (id>>5)], 1u<<(id&31));
  }
}

// ---------------- one-time: gather copy-id columns of Wo2 ----------------
__global__ __launch_bounds__(256) void k_gatherW(const float* __restrict__ Wo2,
                                                 const float* __restrict__ bo2,
                                                 const int* __restrict__ ids,
                                                 float* __restrict__ tmpW, float* __restrict__ tmpB){
  int hg = blockIdx.x;    // 16 groups of 16 h-rows
  int p  = blockIdx.y*256 + threadIdx.x;   // 0..25599
  int id = ids[p];
  int h0 = hg*16;
  float vals[16];
  #pragma unroll
  for(int j=0;j<16;++j)
    vals[j] = (id < VV) ? Wo2[(size_t)(h0+j)*VV + id] : 0.f;
  float* dst = tmpW + (size_t)p*HH + h0;
  #pragma unroll
  for(int j=0;j<16;j+=4) *(float4*)(dst+j) = make_float4(vals[j],vals[j+1],vals[j+2],vals[j+3]);
  if(hg==0) tmpB[p] = (id<VV)? bo2[id] : 0.f;
}

// ---------------- recurrent core: emb/x/LSTM/dec_feat for 4 beams/block ----------------
__global__ __launch_bounds__(256) void k_recur(
    const float* __restrict__ embw, const float* __restrict__ Win, const float* __restrict__ bin,
    const float* __restrict__ Wl, const float* __restrict__ bl, const float* __restrict__ Wd,
    const int* __restrict__ tokS,
    const float* __restrict__ hS, const float* __restrict__ cS, const float* __restrict__ ctxS,
    float* __restrict__ hN, float* __restrict__ cN,
    float* __restrict__ dfW, float* __restrict__ xW)
{
  int bk0 = blockIdx.x*4;
  int t = threadIdx.x;
  __shared__ float sIn[4][384];    // [emb|ctx]
  __shared__ float sXH[4][384];    // [x|h]
  __shared__ float sC[4][HH];
  __shared__ __align__(16) float sZ[4][1024];
  __shared__ float sCH[4][512];    // [c_n|h_n]

  int erm[4];
  #pragma unroll
  for(int m=0;m<4;++m){ int tk = tokS[bk0+m]; erm[m] = (tk<VV)?tk:0; }
  for(int i=t;i<4*384;i+=256){
    int m=i/384, j=i-384*m;
    sIn[m][j] = (j<EE) ? embw[(size_t)erm[m]*EE + j] : ctxS[(size_t)(bk0+m)*HH + (j-EE)];
  }
  for(int i=t;i<4*HH;i+=256){
    int m=i>>8, u=i&255;
    sXH[m][EE+u] = hS[(size_t)(bk0+m)*HH + u];
    sC[m][u]     = cS[(size_t)(bk0+m)*HH + u];
  }
  __syncthreads();
  {
    int c = t & 127, m0 = (t>>7)*2;
    float a0 = bin[c], a1 = bin[c];
    #pragma unroll 4
    for(int i=0;i<384;++i){
      float w = Win[i*EE + c];
      a0 += sIn[m0][i]*w; a1 += sIn[m0+1][i]*w;
    }
    sXH[m0][c]=a0; sXH[m0+1][c]=a1;
    xW[(size_t)(bk0+m0)*EE + c] = a0; xW[(size_t)(bk0+m0+1)*EE + c] = a1;
  }
  __syncthreads();
  {
    float4 bb = *(const float4*)(bl + 4*t);
    float acc[4][4];
    #pragma unroll
    for(int m=0;m<4;++m){ acc[m][0]=bb.x; acc[m][1]=bb.y; acc[m][2]=bb.z; acc[m][3]=bb.w; }
    #pragma unroll 4
    for(int i=0;i<384;++i){
      float4 w = *(const float4*)(Wl + (size_t)i*1024 + 4*t);
      #pragma unroll
      for(int m=0;m<4;++m){
        float v = sXH[m][i];
        acc[m][0] += v*w.x; acc[m][1] += v*w.y; acc[m][2] += v*w.z; acc[m][3] += v*w.w;
      }
    }
    #pragma unroll
    for(int m=0;m<4;++m)
      *(float4*)(&sZ[m][4*t]) = make_float4(acc[m][0],acc[m][1],acc[m][2],acc[m][3]);
  }
  __syncthreads();
  {
    int u = t;
    #pragma unroll
    for(int m=0;m<4;++m){
      float zi = sZ[m][u], zf = sZ[m][256+u], zg = sZ[m][512+u], zo = sZ[m][768+u];
      float co = sC[m][u];
      float cn = sigf(zf)*co + sigf(zi)*tanhf(zg);
      float hn = sigf(zo)*tanhf(cn);
      cN[(size_t)(bk0+m)*HH + u] = cn;
      hN[(size_t)(bk0+m)*HH + u] = hn;
      sCH[m][u] = cn; sCH[m][256+u] = hn;
    }
  }
  __syncthreads();
  {
    int c = t;
    float a[4] = {0.f,0.f,0.f,0.f};
    #pragma unroll 4
    for(int i=0;i<512;++i){
      float w = Wd[i*HH + c];
      #pragma unroll
      for(int m=0;m<4;++m) a[m] += sCH[m][i]*w;
    }
    #pragma unroll
    for(int m=0;m<4;++m) dfW[(size_t)(bk0+m)*HH + c] = a[m];
  }
}

// ---------------- attention scores: e[b,k,s] = va . tanh(ef[b,s]+df[b,k]+ba) ----------------
__global__ __launch_bounds__(256) void k_e(
    const float* __restrict__ ba, const float* __restrict__ va,
    const float* __restrict__ ef, const float* __restrict__ dfW,
    float* __restrict__ eW)
{
  int sq = blockIdx.x, b = blockIdx.y;
  int t = threadIdx.x, lane = t & 63, wv = t >> 6;
  __shared__ float sDf[4][HH];
  __shared__ float sBa[HH], sVa[HH];
  sBa[t] = ba[t]; sVa[t] = va[t];
  for(int i=t;i<4*HH;i+=256){ int k=i>>8, u=i&255; sDf[k][u] = dfW[(size_t)(b*4+k)*HH + u]; }
  __syncthreads();
  float4 bb = *(const float4*)(&sBa[lane*4]);
  float4 vv = *(const float4*)(&sVa[lane*4]);
  int s0 = sq*100;
  for(int s = s0 + wv; s < s0 + 100; s += 4){
    float4 e4 = *(const float4*)(ef + ((size_t)b*SS + s)*HH + lane*4);
    float p[4];
    #pragma unroll
    for(int k=0;k<4;++k){
      float4 d = *(const float4*)(&sDf[k][lane*4]);
      float ux = tanhf(e4.x + d.x + bb.x);
      float uy = tanhf(e4.y + d.y + bb.y);
      float uz = tanhf(e4.z + d.z + bb.z);
      float uw = tanhf(e4.w + d.w + bb.w);
      p[k] = ux*vv.x + uy*vv.y + uz*vv.z + uw*vv.w;
    }
    #pragma unroll
    for(int o=1;o<64;o<<=1){
      #pragma unroll
      for(int k=0;k<4;++k) p[k] += __shfl_xor(p[k], o, 64);
    }
    if(lane < 4) eW[(size_t)(b*4+lane)*SS + s] = p[lane];
  }
}

// ---------------- softmax + partial ctx over s-quarter (grid BB x 4, 512 thr) ----------------
__global__ __launch_bounds__(512) void k_ctxA(
    const float* __restrict__ enc, const float* __restrict__ eW,
    float* __restrict__ attnW, float* __restrict__ ctxP)
{
  int b = blockIdx.x, q = blockIdx.y, t = threadIdx.x;
  __shared__ float sE[4][SS];
  __shared__ float sAt[4][SS];
  __shared__ float sRed[512];
  for(int i=t;i<4*SS;i+=512){ int kk=i/SS, s=i-kk*SS; sE[kk][s] = eW[(size_t)(b*4+kk)*SS + s]; }
  __syncthreads();
  int k = t>>7, u = t&127;   // beam k, 128-thread slot
  float m = -INFINITY;
  for(int s=u; s<SS; s+=128) m = fmaxf(m, sE[k][s]);
  sRed[t] = m; __syncthreads();
  for(int o=64;o>0;o>>=1){ if(u<o) sRed[t] = fmaxf(sRed[t], sRed[t+o]); __syncthreads(); }
  m = sRed[k<<7]; __syncthreads();
  float sum = 0.f;
  for(int s=u; s<SS; s+=128) sum += expf(sE[k][s]-m);
  sRed[t] = sum; __syncthreads();
  for(int o=64;o>0;o>>=1){ if(u<o) sRed[t] += sRed[t+o]; __syncthreads(); }
  sum = sRed[k<<7];
  float inv = 1.0f/sum;
  for(int s=u; s<SS; s+=128){
    float a = expf(sE[k][s]-m)*inv;
    sAt[k][s] = a;
    if(q==0) attnW[(size_t)(b*4+k)*SS + s] = a;
  }
  __syncthreads();
  // partial ctx over s in [q*100, q*100+100): thread (h2 = t>>8, u2 = t&255) does beams h2, h2+2
  {
    int h2 = t>>8, u2 = t&255;
    float a0 = 0.f, a1 = 0.f;
    int sA = q*100;
    #pragma unroll 4
    for(int s=sA; s<sA+100; ++s){
      float ev = enc[((size_t)b*SS + s)*HH + u2];
      a0 += sAt[h2][s]*ev;
      a1 += sAt[h2+2][s]*ev;
    }
    ctxP[(((size_t)b*4 + q)*4 + h2  )*HH + u2] = a0;
    ctxP[(((size_t)b*4 + q)*4 + h2+2)*HH + u2] = a1;
  }
}

// ---------------- q-sum + pgen + out1 (grid BB, 512 thr) ----------------
__global__ __launch_bounds__(512) void k_ctxB(
    const float* __restrict__ wp, const float* __restrict__ bp,
    const float* __restrict__ Wo1, const float* __restrict__ bo1,
    const float* __restrict__ ctxP,
    const float* __restrict__ cN, const float* __restrict__ hN, const float* __restrict__ xW,
    float* __restrict__ ctxN, float* __restrict__ out1W, float* __restrict__ pgenW)
{
  int b = blockIdx.x, t = threadIdx.x;
  __shared__ float sCtx[4][HH];
  __shared__ float sCn[4][HH], sHn[4][HH];
  __shared__ float sX[4][EE];
  __shared__ float sRed[512];
  int h2 = t>>8, u = t&255;
  {
    float a0 = 0.f, a1 = 0.f;
    #pragma unroll
    for(int q=0;q<4;++q){
      a0 += ctxP[(((size_t)b*4 + q)*4 + h2  )*HH + u];
      a1 += ctxP[(((size_t)b*4 + q)*4 + h2+2)*HH + u];
    }
    sCtx[h2][u] = a0; sCtx[h2+2][u] = a1;
    ctxN[(size_t)(b*4+h2)*HH + u] = a0;
    ctxN[(size_t)(b*4+h2+2)*HH + u] = a1;
  }
  for(int i=t;i<4*HH;i+=512){
    int k=i>>8, uu=i&255;
    sCn[k][uu] = cN[(size_t)(b*4+k)*HH + uu];
    sHn[k][uu] = hN[(size_t)(b*4+k)*HH + uu];
  }
  { int k=t>>7, uu=t&127; sX[k][uu] = xW[(size_t)(b*4+k)*EE + uu]; }
  __syncthreads();
  // p_gen: 128 threads per beam
  {
    int k = t>>7, uu = t&127;
    float p = 0.f;
    for(int i=uu;i<896;i+=128){
      float v;
      if(i<256) v = sCtx[k][i];
      else if(i<512) v = sCn[k][i-256];
      else if(i<768) v = sHn[k][i-512];
      else v = sX[k][i-768];
      p += v*wp[i];
    }
    sRed[t] = p; __syncthreads();
    for(int o=64;o>0;o>>=1){ if(uu<o) sRed[t]+=sRed[t+o]; __syncthreads(); }
    if(uu==0) pgenW[b*4+k] = sigf(sRed[t] + bp[0]);
  }
  __syncthreads();
  // out1: thread (h2,u) does beams h2, h2+2 (Wo1 load shared)
  {
    float a0 = bo1[u], a1 = bo1[u];
    #pragma unroll 4
    for(int i=0;i<HH;++i){
      float w = Wo1[i*HH + u];
      a0 += sHn[h2][i]*w; a1 += sHn[h2+2][i]*w;
    }
    #pragma unroll 4
    for(int i=0;i<HH;++i){
      float w = Wo1[(HH+i)*HH + u];
      a0 += sCtx[h2][i]*w; a1 += sCtx[h2+2][i]*w;
    }
    out1W[(size_t)(b*4+h2)*HH + u] = a0;
    out1W[(size_t)(b*4+h2+2)*HH + u] = a1;
  }
}

// ---------------- vocab GEMM: beam-pass loop inside block (grid NCH x 2) ----------------
__global__ __launch_bounds__(256) void k_vocab2(
    const float* __restrict__ Wo2, const float* __restrict__ bo2,
    const float* __restrict__ out1W,
    float* __restrict__ sumexpW, float* __restrict__ cmaxW, int* __restrict__ cmaxIdW)
{
  int c = blockIdx.x;          // chunk (196)
  int hb = blockIdx.y;         // beam half (2)
  int t = threadIdx.x, lane = t&63, wv = t>>6;
  __shared__ __align__(16) float sT[32*HH];    // 32 KB
  const int vbase = c*VCH + lane*4;
  const bool full = (c*VCH + VCH <= VV);

  for(int g=0; g<4; ++g){
    int bk0 = (hb*4 + g)*32;
    __syncthreads();
    for(int i=t; i<32*HH/4; i+=256)
      ((float4*)sT)[i] = ((const float4*)(out1W + (size_t)bk0*HH))[i];
    __syncthreads();

    float acc[8][4];
    #pragma unroll
    for(int m=0;m<8;++m){
      #pragma unroll
      for(int j=0;j<4;++j) acc[m][j]=0.f;
    }
    const float* sTw = sT + wv*8*HH;
    if(full){
      for(int h=0; h<HH; h+=4){
        float4 w0 = *(const float4*)(Wo2 + (size_t)(h+0)*VV + vbase);
        float4 w1 = *(const float4*)(Wo2 + (size_t)(h+1)*VV + vbase);
        float4 w2 = *(const float4*)(Wo2 + (size_t)(h+2)*VV + vbase);
        float4 w3 = *(const float4*)(Wo2 + (size_t)(h+3)*VV + vbase);
        #pragma unroll
        for(int m=0;m<8;++m){
          float4 o = *(const float4*)(sTw + m*HH + h);
          acc[m][0] += w0.x*o.x + w1.x*o.y + w2.x*o.z + w3.x*o.w;
          acc[m][1] += w0.y*o.x + w1.y*o.y + w2.y*o.z + w3.y*o.w;
          acc[m][2] += w0.z*o.x + w1.z*o.y + w2.z*o.z + w3.z*o.w;
          acc[m][3] += w0.w*o.x + w1.w*o.y + w2.w*o.z + w3.w*o.w;
        }
      }
    } else {
      for(int h=0; h<HH; ++h){
        float wv4[4];
        #pragma unroll
        for(int j=0;j<4;++j){ int v = vbase+j; wv4[j] = (v<VV)? Wo2[(size_t)h*VV + v] : 0.f; }
        #pragma unroll
        for(int m=0;m<8;++m){
          float o = sTw[m*HH + h];
          #pragma unroll
          for(int j=0;j<4;++j) acc[m][j] += wv4[j]*o;
        }
      }
    }

    float lsum[8]; float lmax[8]; int lid[8];
    #pragma unroll
    for(int m=0;m<8;++m){ lsum[m]=0.f; lmax[m]=-INFINITY; lid[m]=-1; }
    #pragma unroll
    for(int j=0;j<4;++j){
      int v = vbase + j;
      if(v < VV){
        float bb2 = bo2[v];
        #pragma unroll
        for(int m=0;m<8;++m){
          float lg = acc[m][j] + bb2;
          lsum[m] += expf(lg);
          if(lg > lmax[m]){ lmax[m]=lg; lid[m]=v; }
        }
      }
    }
    #pragma unroll
    for(int m=0;m<8;++m){
      float s2 = lsum[m]; float mx = lmax[m]; int id = lid[m];
      #pragma unroll
      for(int o=1;o<64;o<<=1){
        s2 += __shfl_xor(s2, o, 64);
        float mx2 = __shfl_xor(mx, o, 64);
        int   id2 = __shfl_xor(id, o, 64);
        if(mx2 > mx || (mx2 == mx && (unsigned)id2 < (unsigned)id)){ mx = mx2; id = id2; }
      }
      if(lane == 0){
        int beam = bk0 + wv*8 + m;
        sumexpW[(size_t)beam*NCH + c] = s2;
        cmaxW  [(size_t)beam*NCH + c] = mx;
        cmaxIdW[(size_t)beam*NCH + c] = id;
      }
    }
  }
}

// ---------------- fused copy-logits + candidate scoring + top-4 + state update ----------------
__global__ __launch_bounds__(256) void k_select(
    int tstep,
    const int* __restrict__ ids, const float* __restrict__ attnW, const float* __restrict__ pgenW,
    const float* __restrict__ sumexpW, const float* __restrict__ cmaxW, const int* __restrict__ cmaxIdW,
    const float* __restrict__ tmpW, const float* __restrict__ tmpB, const float* __restrict__ out1W,
    const int* __restrict__ nexts, const int* __restrict__ firstS, const unsigned* __restrict__ bmC,
    const float* __restrict__ hN, const float* __restrict__ cN, const float* __restrict__ ctxN,
    float* __restrict__ hS, float* __restrict__ cS, float* __restrict__ ctxS,
    float* __restrict__ logp, int* __restrict__ tokS, int* __restrict__ tokens,
    float* __restrict__ dout)
{
  int b = blockIdx.x, t = threadIdx.x, lane = t & 63, wv = t >> 6;
  __shared__ int   sIds[SS];
  __shared__ int   sNext[SS];
  __shared__ int   sFirst[SS];
  __shared__ unsigned sBm[NBMW];
  __shared__ float sAttn[4][SS];
  __shared__ float sLit[4][SS];
  __shared__ __align__(16) float sO[4*HH];
  __shared__ float sVal[4][NSLOT];
  __shared__ int   sCid[4][NSLOT];
  __shared__ float sLse[4], sPg[4], sLp[4];
  __shared__ float wredV[4]; __shared__ int wredK[4]; __shared__ int wredT[4];
  __shared__ int sTokOld[4][NSTEPS];

  for(int i=t;i<SS;i+=256){
    sIds[i]   = ids[(size_t)b*SS + i];
    sNext[i]  = nexts[(size_t)b*SS + i];
    sFirst[i] = firstS[(size_t)b*SS + i];
  }
  for(int i=t;i<NBMW;i+=256) sBm[i] = bmC[(size_t)b*NBMW + i];
  for(int i=t;i<4*SS;i+=256){ int k=i/SS, s=i-k*SS; sAttn[k][s] = attnW[(size_t)(b*4+k)*SS + s]; }
  for(int i=t;i<4*HH/4;i+=256)
    ((float4*)sO)[i] = ((const float4*)(out1W + (size_t)b*4*HH))[i];
  if(t<128){ int k=t>>5, u=t&31; sTokOld[k][u] = tokens[(size_t)(b*4+k)*NSTEPS + u]; }
  __syncthreads();
  // copy-logit dots: lit[k][s] = out1[b,k] . tmpW[b,s] + tmpB[b,s]
  {
    float4 o0 = ((const float4*)(sO + 0*HH))[lane];
    float4 o1 = ((const float4*)(sO + 1*HH))[lane];
    float4 o2 = ((const float4*)(sO + 2*HH))[lane];
    float4 o3 = ((const float4*)(sO + 3*HH))[lane];
    int s0 = wv*100;
    for(int sg=0; sg<100; sg+=4){
      float4 tw0 = ((const float4*)(tmpW + ((size_t)b*SS + s0+sg+0)*HH))[lane];
      float4 tw1 = ((const float4*)(tmpW + ((size_t)b*SS + s0+sg+1)*HH))[lane];
      float4 tw2 = ((const float4*)(tmpW + ((size_t)b*SS + s0+sg+2)*HH))[lane];
      float4 tw3 = ((const float4*)(tmpW + ((size_t)b*SS + s0+sg+3)*HH))[lane];
      #pragma unroll
      for(int q=0;q<4;++q){
        float4 tw = (q==0)?tw0:(q==1)?tw1:(q==2)?tw2:tw3;
        float p0 = tw.x*o0.x + tw.y*o0.y + tw.z*o0.z + tw.w*o0.w;
        float p1 = tw.x*o1.x + tw.y*o1.y + tw.z*o1.z + tw.w*o1.w;
        float p2 = tw.x*o2.x + tw.y*o2.y + tw.z*o2.z + tw.w*o2.w;
        float p3 = tw.x*o3.x + tw.y*o3.y + tw.z*o3.z + tw.w*o3.w;
        #pragma unroll
        for(int o=1;o<64;o<<=1){
          p0 += __shfl_xor(p0,o,64); p1 += __shfl_xor(p1,o,64);
          p2 += __shfl_xor(p2,o,64); p3 += __shfl_xor(p3,o,64);
        }
        if(lane==0){
          int s = s0+sg+q;
          float bb = tmpB[(size_t)b*SS + s];
          sLit[0][s] = p0 + bb; sLit[1][s] = p1 + bb;
          sLit[2][s] = p2 + bb; sLit[3][s] = p3 + bb;
        }
      }
    }
  }
  // lse / pgen / logp per beam
  {
    int beam = b*4 + wv;
    float p = 0.f;
    for(int cc=lane; cc<NCH; cc+=64) p += sumexpW[(size_t)beam*NCH + cc];
    #pragma unroll
    for(int o=1;o<64;o<<=1) p += __shfl_xor(p, o, 64);
    if(lane==0){ sLse[wv] = logf(p); sPg[wv] = pgenW[beam]; sLp[wv] = logp[beam]; }
  }
  __syncthreads();
  // copy candidates
  for(int i=t; i<4*SS; i+=256){
    int k=i/SS, s=i-k*SS;
    int id = sIds[s];
    float val = -INFINITY;
    if(sFirst[s]){
      float as = sAttn[k][s];
      int s2 = sNext[s];
      while(s2 >= 0){ as += sAttn[k][s2]; s2 = sNext[s2]; }
      float vp = 0.f;
      if(id < VV) vp = expf(sLit[k][s] - sLse[k]);
      float pg = sPg[k];
      val = sLp[k] + logf(pg*vp + (1.f-pg)*as + 1e-10f);
    }
    sVal[k][s] = val; sCid[k][s] = id;
  }
  // vocab safety-net candidates
  for(int i=t; i<4*NCH; i+=256){
    int k=i/NCH, cc=i-k*NCH;
    int beam = b*4 + k;
    int id = cmaxIdW[(size_t)beam*NCH + cc];
    float val = -INFINITY;
    if(id >= 0){
      bool member = (sBm[id>>5] >> (id&31)) & 1u;
      if(!member){
        float pg = sPg[k];
        val = sLp[k] + logf(pg*expf(cmaxW[(size_t)beam*NCH + cc] - sLse[k]) + 1e-10f);
      }
    }
    sVal[k][SS+cc] = val; sCid[k][SS+cc] = id;
  }
  __syncthreads();
  // per-thread local top-4 over strided slots
  float lv[4] = {-INFINITY,-INFINITY,-INFINITY,-INFINITY};
  int   lk[4] = {INT_MAX,INT_MAX,INT_MAX,INT_MAX};
  for(int i=t; i<4*NSLOT; i+=256){
    int k = i/NSLOT, sl = i - k*NSLOT;
    float v = sVal[k][sl];
    if(!(v > -INFINITY)) continue;
    int key = k*VEXTT + sCid[k][sl];
    if(betterf(v, key, lv[3], lk[3])){
      lv[3]=v; lk[3]=key;
      #pragma unroll
      for(int j=3;j>0;--j){
        if(betterf(lv[j],lk[j],lv[j-1],lk[j-1])){
          float tv=lv[j]; lv[j]=lv[j-1]; lv[j-1]=tv;
          int tk2=lk[j]; lk[j]=lk[j-1]; lk[j-1]=tk2;
        }
      }
    }
  }
  // 4 selection rounds
  int hp = 0;
  float selv[4]; int selk[4], seli[4];
  for(int r=0;r<4;++r){
    float hv = (hp<4) ? lv[hp] : -INFINITY;
    int   hk = (hp<4) ? lk[hp] : INT_MAX;
    float bv = hv; int bk2 = hk; int btid = t;
    #pragma unroll
    for(int o=1;o<64;o<<=1){
      float ov = __shfl_xor(bv,o,64);
      int   ok = __shfl_xor(bk2,o,64);
      int   ot = __shfl_xor(btid,o,64);
      if(betterf(ov,ok,bv,bk2)){ bv=ov; bk2=ok; btid=ot; }
    }
    if(lane==0){ wredV[wv]=bv; wredK[wv]=bk2; wredT[wv]=btid; }
    __syncthreads();
    float gv = wredV[0]; int gk = wredK[0], gt = wredT[0];
    #pragma unroll
    for(int w2=1;w2<4;++w2)
      if(betterf(wredV[w2],wredK[w2],gv,gk)){ gv=wredV[w2]; gk=wredK[w2]; gt=wredT[w2]; }
    if(t == gt) hp++;
    int kk = gk / VEXTT;
    selv[r] = gv; selk[r] = kk; seli[r] = gk - kk*VEXTT;
    __syncthreads();
  }
  // state update via backpointers
  for(int j=0;j<4;++j){
    int kj = selk[j];
    hS  [(size_t)(b*4+j)*HH + t] = hN  [(size_t)(b*4+kj)*HH + t];
    cS  [(size_t)(b*4+j)*HH + t] = cN  [(size_t)(b*4+kj)*HH + t];
    ctxS[(size_t)(b*4+j)*HH + t] = ctxN[(size_t)(b*4+kj)*HH + t];
  }
  if(t<4){ logp[b*4+t] = selv[t]; tokS[b*4+t] = seli[t]; }
  if(t<128){
    int j=t>>5, u=t&31;
    int nv = (u==tstep) ? seli[j] : sTokOld[selk[j]][u];
    tokens[(size_t)(b*4+j)*NSTEPS + u] = nv;
    if(tstep == NSTEPS-1) dout[(size_t)(b*4+j)*NSTEPS + u] = (float)nv;
  }
  if(tstep == NSTEPS-1 && t<4) dout[(size_t)BB*4*NSTEPS + b*4 + t] = selv[t];
}

extern "C" void kernel_launch(void* const* d_in, const int* in_sizes, int n_in,
                              void* d_out, int out_size, void* d_ws, size_t ws_size,
                              hipStream_t stream) {
  const float* enc  = (const float*)d_in[0];
  const int*   ids  = (const int*)  d_in[2];
  const float* h0   = (const float*)d_in[3];
  const float* c0   = (const float*)d_in[4];
  const float* embw = (const float*)d_in[5];
  const float* Win  = (const float*)d_in[6];
  const float* bin  = (const float*)d_in[7];
  const float* Wl   = (const float*)d_in[8];
  const float* bl   = (const float*)d_in[9];
  const float* Wenc = (const float*)d_in[10];
  const float* Wd   = (const float*)d_in[11];
  const float* ba   = (const float*)d_in[12];
  const float* va   = (const float*)d_in[13];
  const float* wp   = (const float*)d_in[14];
  const float* bp   = (const float*)d_in[15];
  const float* Wo1  = (const float*)d_in[16];
  const float* bo1  = (const float*)d_in[17];
  const float* Wo2  = (const float*)d_in[18];
  const float* bo2  = (const float*)d_in[19];

  char* w = (char*)d_ws;
  auto alloc = [&](size_t bytes)->void*{ void* p = (void*)w; w += (bytes + 255) & ~(size_t)255; return p; };
  float* ef     = (float*)alloc((size_t)BB*SS*HH*4);
  float* tmpW   = (float*)alloc((size_t)BB*SS*HH*4);
  float* tmpB   = (float*)alloc((size_t)BB*SS*4);
  int*   nextsW = (int*)  alloc((size_t)BB*SS*4);
  int*   firstW = (int*)  alloc((size_t)BB*SS*4);
  unsigned* bmC = (unsigned*)alloc((size_t)BB*NBMW*4);
  float* hS     = (float*)alloc((size_t)NBK*HH*4);
  float* cS     = (float*)alloc((size_t)NBK*HH*4);
  float* ctxS   = (float*)alloc((size_t)NBK*HH*4);
  float* logpW  = (float*)alloc((size_t)NBK*4);
  int*   tokW   = (int*)  alloc((size_t)NBK*4);
  int*   tokensW= (int*)  alloc((size_t)NBK*NSTEPS*4);
  float* hN     = (float*)alloc((size_t)NBK*HH*4);
  float* cN     = (float*)alloc((size_t)NBK*HH*4);
  float* ctxN   = (float*)alloc((size_t)NBK*HH*4);
  float* attnW  = (float*)alloc((size_t)NBK*SS*4);
  float* out1W  = (float*)alloc((size_t)NBK*HH*4);
  float* pgenW  = (float*)alloc((size_t)NBK*4);
  float* sumexpW= (float*)alloc((size_t)NBK*NCH*4);
  float* cmaxW  = (float*)alloc((size_t)NBK*NCH*4);
  int*   cmaxIdW= (int*)  alloc((size_t)NBK*NCH*4);
  float* dfW    = (float*)alloc((size_t)NBK*HH*4);
  float* xW     = (float*)alloc((size_t)NBK*EE*4);
  float* eWbuf  = (float*)alloc((size_t)NBK*SS*4);
  float* ctxP   = (float*)alloc((size_t)BB*4*4*HH*4);

  hipLaunchKernelGGL(k_init, dim3(NBK), dim3(HH), 0, stream, h0, c0, hS, cS, ctxS, logpW, tokW, tokensW);
  hipLaunchKernelGGL(k_encfeats, dim3(BB*(SS/TSR)), dim3(256), 0, stream, enc, Wenc, ef);
  hipLaunchKernelGGL(k_prep, dim3(BB), dim3(256), 0, stream, ids, nextsW, firstW, bmC);
  hipLaunchKernelGGL(k_gatherW, dim3(16, 100), dim3(256), 0, stream, Wo2, bo2, ids, tmpW, tmpB);

  for(int tstep=0; tstep<NSTEPS; ++tstep){
    hipLaunchKernelGGL(k_recur, dim3(NBK/4), dim3(256), 0, stream,
                       embw, Win, bin, Wl, bl, Wd, tokW, hS, cS, ctxS,
                       hN, cN, dfW, xW);
    hipLaunchKernelGGL(k_e, dim3(4, BB), dim3(256), 0, stream,
                       ba, va, ef, dfW, eWbuf);
    hipLaunchKernelGGL(k_ctxA, dim3(BB, 4), dim3(512), 0, stream,
                       enc, eWbuf, attnW, ctxP);
    hipLaunchKernelGGL(k_ctxB, dim3(BB), dim3(512), 0, stream,
                       wp, bp, Wo1, bo1, ctxP, cN, hN, xW,
                       ctxN, out1W, pgenW);
    hipLaunchKernelGGL(k_vocab2, dim3(NCH, 2), dim3(256), 0, stream,
                       Wo2, bo2, out1W, sumexpW, cmaxW, cmaxIdW);
    hipLaunchKernelGGL(k_select, dim3(BB), dim3(256), 0, stream, tstep,
                       ids, attnW, pgenW, sumexpW, cmaxW, cmaxIdW,
                       tmpW, tmpB, out1W,
                       nextsW, firstW, bmC,
                       hN, cN, ctxN, hS, cS, ctxS, logpW, tokW, tokensW,
                       (float*)d_out);
  }
}

// Round 6
// 13007.730 us; speedup vs baseline: 1.4646x; 1.4646x over previous
//
#include <hip/hip_runtime.h>
#include <math.h>
#include <limits.h>

#define BB 64
#define SS 400
#define HH 256
#define EE 128
#define VV 50000
#define VEXTT 50100
#define NSTEPS 32
#define NBK 256      // B*K beams
#define NCH 196      // ceil(50000/256) vocab chunks of 256
#define NCHP 200     // padded chunk-grid (multiple of 8) for XCD swizzle
#define VCH 256      // columns per chunk
#define NSLOT 596    // SS + NCH candidate slots per beam
#define NBMW 1568    // bitmap words per batch (50100 bits)

__device__ __forceinline__ float sigf(float x){ return 1.0f/(1.0f+expf(-x)); }
__device__ __forceinline__ bool betterf(float v, int key, float v2, int key2){
  return v > v2 || (v == v2 && key < key2);
}

// ---------------- init state ----------------
__global__ void k_init(const float* __restrict__ h0, const float* __restrict__ c0,
                       float* hS, float* cS, float* ctxS, float* logp, int* tok, int* tokens){
  int bk = blockIdx.x; int b = bk >> 2; int t = threadIdx.x;
  hS[bk*HH+t] = h0[b*HH+t];
  cS[bk*HH+t] = c0[b*HH+t];
  ctxS[bk*HH+t] = 0.f;
  if(t==0){ logp[bk] = ((bk&3)==0) ? 0.f : -1e9f; tok[bk] = 2; }
  if(t < NSTEPS) tokens[bk*NSTEPS + t] = 0;
}

// ---------------- enc_feats = enc_outputs @ W_enc ----------------
#define TSR 16
__global__ __launch_bounds__(256) void k_encfeats(const float* __restrict__ enc,
                                                  const float* __restrict__ W,
                                                  float* __restrict__ ef){
  int blk = blockIdx.x;               // 64 * 25
  int b = blk/25, s0 = (blk%25)*TSR;
  int t = threadIdx.x;
  __shared__ float rows[TSR*HH];
  for(int i=t;i<TSR*HH;i+=256) rows[i] = enc[((size_t)b*SS + s0)*HH + i];
  __syncthreads();
  float a[TSR];
  #pragma unroll
  for(int r=0;r<TSR;++r) a[r]=0.f;
  for(int h=0;h<HH;++h){
    float w = W[h*HH + t];
    #pragma unroll
    for(int r=0;r<TSR;++r) a[r] += rows[r*HH + h]*w;
  }
  for(int r=0;r<TSR;++r) ef[((size_t)b*SS + s0 + r)*HH + t] = a[r];
}

// ---------------- one-time: dup structure + copy-id bitmap ----------------
__global__ __launch_bounds__(256) void k_prep(const int* __restrict__ ids,
                                              int* __restrict__ nexts, int* __restrict__ firstS,
                                              unsigned* __restrict__ bmC){
  int b = blockIdx.x; int t = threadIdx.x;
  __shared__ int sI[SS];
  for(int i=t;i<SS;i+=256) sI[i]=ids[(size_t)b*SS+i];
  for(int i=t;i<NBMW;i+=256) bmC[(size_t)b*NBMW+i]=0u;
  __syncthreads();
  for(int s=t; s<SS; s+=256){
    int id=sI[s]; int fo=1, nx=-1;
    for(int s2=0;s2<s;++s2) if(sI[s2]==id){fo=0;break;}
    for(int s2=s+1;s2<SS;++s2) if(sI[s2]==id){nx=s2;break;}
    firstS[(size_t)b*SS+s]=fo; nexts[(size_t)b*SS+s]=nx;
    if(fo && id<VV) atomicOr(&bmC[(size_t)b*NBMW + (id>>5)], 1u<<(id&31));
  }
}

// ---------------- one-time: gather copy-id columns of Wo2 ----------------
__global__ __launch_bounds__(256) void k_gatherW(const float* __restrict__ Wo2,
                                                 const float* __restrict__ bo2,
                                                 const int* __restrict__ ids,
                                                 float* __restrict__ tmpW, float* __restrict__ tmpB){
  int hg = blockIdx.x;    // 16 groups of 16 h-rows
  int p  = blockIdx.y*256 + threadIdx.x;   // 0..25599
  int id = ids[p];
  int h0 = hg*16;
  float vals[16];
  #pragma unroll
  for(int j=0;j<16;++j)
    vals[j] = (id < VV) ? Wo2[(size_t)(h0+j)*VV + id] : 0.f;
  float* dst = tmpW + (size_t)p*HH + h0;
  #pragma unroll
  for(int j=0;j<16;j+=4) *(float4*)(dst+j) = make_float4(vals[j],vals[j+1],vals[j+2],vals[j+3]);
  if(hg==0) tmpB[p] = (id<VV)? bo2[id] : 0.f;
}

// ---------------- recurrent core: emb/x/LSTM/dec_feat for 4 beams/block ----------------
__global__ __launch_bounds__(256) void k_recur(
    const float* __restrict__ embw, const float* __restrict__ Win, const float* __restrict__ bin,
    const float* __restrict__ Wl, const float* __restrict__ bl, const float* __restrict__ Wd,
    const int* __restrict__ tokS,
    const float* __restrict__ hS, const float* __restrict__ cS, const float* __restrict__ ctxS,
    float* __restrict__ hN, float* __restrict__ cN,
    float* __restrict__ dfW, float* __restrict__ xW)
{
  int bk0 = blockIdx.x*4;
  int t = threadIdx.x;
  __shared__ float sIn[4][384];    // [emb|ctx]
  __shared__ float sXH[4][384];    // [x|h]
  __shared__ float sC[4][HH];
  __shared__ __align__(16) float sZ[4][1024];
  __shared__ float sCH[4][512];    // [c_n|h_n]

  int erm[4];
  #pragma unroll
  for(int m=0;m<4;++m){ int tk = tokS[bk0+m]; erm[m] = (tk<VV)?tk:0; }
  for(int i=t;i<4*384;i+=256){
    int m=i/384, j=i-384*m;
    sIn[m][j] = (j<EE) ? embw[(size_t)erm[m]*EE + j] : ctxS[(size_t)(bk0+m)*HH + (j-EE)];
  }
  for(int i=t;i<4*HH;i+=256){
    int m=i>>8, u=i&255;
    sXH[m][EE+u] = hS[(size_t)(bk0+m)*HH + u];
    sC[m][u]     = cS[(size_t)(bk0+m)*HH + u];
  }
  __syncthreads();
  {
    int c = t & 127, m0 = (t>>7)*2;
    float a0 = bin[c], a1 = bin[c];
    #pragma unroll 4
    for(int i=0;i<384;++i){
      float w = Win[i*EE + c];
      a0 += sIn[m0][i]*w; a1 += sIn[m0+1][i]*w;
    }
    sXH[m0][c]=a0; sXH[m0+1][c]=a1;
    xW[(size_t)(bk0+m0)*EE + c] = a0; xW[(size_t)(bk0+m0+1)*EE + c] = a1;
  }
  __syncthreads();
  {
    float4 bb = *(const float4*)(bl + 4*t);
    float acc[4][4];
    #pragma unroll
    for(int m=0;m<4;++m){ acc[m][0]=bb.x; acc[m][1]=bb.y; acc[m][2]=bb.z; acc[m][3]=bb.w; }
    #pragma unroll 4
    for(int i=0;i<384;++i){
      float4 w = *(const float4*)(Wl + (size_t)i*1024 + 4*t);
      #pragma unroll
      for(int m=0;m<4;++m){
        float v = sXH[m][i];
        acc[m][0] += v*w.x; acc[m][1] += v*w.y; acc[m][2] += v*w.z; acc[m][3] += v*w.w;
      }
    }
    #pragma unroll
    for(int m=0;m<4;++m)
      *(float4*)(&sZ[m][4*t]) = make_float4(acc[m][0],acc[m][1],acc[m][2],acc[m][3]);
  }
  __syncthreads();
  {
    int u = t;
    #pragma unroll
    for(int m=0;m<4;++m){
      float zi = sZ[m][u], zf = sZ[m][256+u], zg = sZ[m][512+u], zo = sZ[m][768+u];
      float co = sC[m][u];
      float cn = sigf(zf)*co + sigf(zi)*tanhf(zg);
      float hn = sigf(zo)*tanhf(cn);
      cN[(size_t)(bk0+m)*HH + u] = cn;
      hN[(size_t)(bk0+m)*HH + u] = hn;
      sCH[m][u] = cn; sCH[m][256+u] = hn;
    }
  }
  __syncthreads();
  {
    int c = t;
    float a[4] = {0.f,0.f,0.f,0.f};
    #pragma unroll 4
    for(int i=0;i<512;++i){
      float w = Wd[i*HH + c];
      #pragma unroll
      for(int m=0;m<4;++m) a[m] += sCH[m][i]*w;
    }
    #pragma unroll
    for(int m=0;m<4;++m) dfW[(size_t)(bk0+m)*HH + c] = a[m];
  }
}

// ---------------- attention scores: e[b,k,s] = va . tanh(ef[b,s]+df[b,k]+ba) ----------------
// grid (8 s-slices of 50, BB batches)
__global__ __launch_bounds__(256) void k_e(
    const float* __restrict__ ba, const float* __restrict__ va,
    const float* __restrict__ ef, const float* __restrict__ dfW,
    float* __restrict__ eW)
{
  int sq = blockIdx.x, b = blockIdx.y;
  int t = threadIdx.x, lane = t & 63, wv = t >> 6;
  __shared__ float sDf[4][HH];
  __shared__ float sBa[HH], sVa[HH];
  sBa[t] = ba[t]; sVa[t] = va[t];
  for(int i=t;i<4*HH;i+=256){ int k=i>>8, u=i&255; sDf[k][u] = dfW[(size_t)(b*4+k)*HH + u]; }
  __syncthreads();
  float4 bb = *(const float4*)(&sBa[lane*4]);
  float4 vv = *(const float4*)(&sVa[lane*4]);
  int s0 = sq*50;
  for(int s = s0 + wv; s < s0 + 50; s += 4){
    float4 e4 = *(const float4*)(ef + ((size_t)b*SS + s)*HH + lane*4);
    float p[4];
    #pragma unroll
    for(int k=0;k<4;++k){
      float4 d = *(const float4*)(&sDf[k][lane*4]);
      float ux = tanhf(e4.x + d.x + bb.x);
      float uy = tanhf(e4.y + d.y + bb.y);
      float uz = tanhf(e4.z + d.z + bb.z);
      float uw = tanhf(e4.w + d.w + bb.w);
      p[k] = ux*vv.x + uy*vv.y + uz*vv.z + uw*vv.w;
    }
    #pragma unroll
    for(int o=1;o<64;o<<=1){
      #pragma unroll
      for(int k=0;k<4;++k) p[k] += __shfl_xor(p[k], o, 64);
    }
    if(lane < 4) eW[(size_t)(b*4+lane)*SS + s] = p[lane];
  }
}

// ---------------- softmax + partial ctx over s-quarter (grid BB x 4, 512 thr) ----------------
__global__ __launch_bounds__(512) void k_ctxA(
    const float* __restrict__ enc, const float* __restrict__ eW,
    float* __restrict__ attnW, float* __restrict__ ctxP)
{
  int b = blockIdx.x, q = blockIdx.y, t = threadIdx.x;
  __shared__ float sE[4][SS];
  __shared__ float sAt[4][SS];
  __shared__ float sRed[512];
  for(int i=t;i<4*SS;i+=512){ int kk=i/SS, s=i-kk*SS; sE[kk][s] = eW[(size_t)(b*4+kk)*SS + s]; }
  __syncthreads();
  int k = t>>7, u = t&127;   // beam k, 128-thread slot
  float m = -INFINITY;
  for(int s=u; s<SS; s+=128) m = fmaxf(m, sE[k][s]);
  sRed[t] = m; __syncthreads();
  for(int o=64;o>0;o>>=1){ if(u<o) sRed[t] = fmaxf(sRed[t], sRed[t+o]); __syncthreads(); }
  m = sRed[k<<7]; __syncthreads();
  float sum = 0.f;
  for(int s=u; s<SS; s+=128) sum += expf(sE[k][s]-m);
  sRed[t] = sum; __syncthreads();
  for(int o=64;o>0;o>>=1){ if(u<o) sRed[t] += sRed[t+o]; __syncthreads(); }
  sum = sRed[k<<7];
  float inv = 1.0f/sum;
  for(int s=u; s<SS; s+=128){
    float a = expf(sE[k][s]-m)*inv;
    sAt[k][s] = a;
    if(q==0) attnW[(size_t)(b*4+k)*SS + s] = a;
  }
  __syncthreads();
  // partial ctx over s in [q*100, q*100+100): thread (h2 = t>>8, u2 = t&255) does beams h2, h2+2
  {
    int h2 = t>>8, u2 = t&255;
    float a0 = 0.f, a1 = 0.f;
    int sA = q*100;
    #pragma unroll 4
    for(int s=sA; s<sA+100; ++s){
      float ev = enc[((size_t)b*SS + s)*HH + u2];
      a0 += sAt[h2][s]*ev;
      a1 += sAt[h2+2][s]*ev;
    }
    ctxP[(((size_t)b*4 + q)*4 + h2  )*HH + u2] = a0;
    ctxP[(((size_t)b*4 + q)*4 + h2+2)*HH + u2] = a1;
  }
}

// ---------------- q-sum + pgen + out1 (grid BB, 512 thr) ----------------
__global__ __launch_bounds__(512) void k_ctxB(
    const float* __restrict__ wp, const float* __restrict__ bp,
    const float* __restrict__ Wo1, const float* __restrict__ bo1,
    const float* __restrict__ ctxP,
    const float* __restrict__ cN, const float* __restrict__ hN, const float* __restrict__ xW,
    float* __restrict__ ctxN, float* __restrict__ out1W, float* __restrict__ pgenW)
{
  int b = blockIdx.x, t = threadIdx.x;
  __shared__ float sCtx[4][HH];
  __shared__ float sCn[4][HH], sHn[4][HH];
  __shared__ float sX[4][EE];
  __shared__ float sRed[512];
  int h2 = t>>8, u = t&255;
  {
    float a0 = 0.f, a1 = 0.f;
    #pragma unroll
    for(int q=0;q<4;++q){
      a0 += ctxP[(((size_t)b*4 + q)*4 + h2  )*HH + u];
      a1 += ctxP[(((size_t)b*4 + q)*4 + h2+2)*HH + u];
    }
    sCtx[h2][u] = a0; sCtx[h2+2][u] = a1;
    ctxN[(size_t)(b*4+h2)*HH + u] = a0;
    ctxN[(size_t)(b*4+h2+2)*HH + u] = a1;
  }
  for(int i=t;i<4*HH;i+=512){
    int k=i>>8, uu=i&255;
    sCn[k][uu] = cN[(size_t)(b*4+k)*HH + uu];
    sHn[k][uu] = hN[(size_t)(b*4+k)*HH + uu];
  }
  { int k=t>>7, uu=t&127; sX[k][uu] = xW[(size_t)(b*4+k)*EE + uu]; }
  __syncthreads();
  // p_gen: 128 threads per beam
  {
    int k = t>>7, uu = t&127;
    float p = 0.f;
    for(int i=uu;i<896;i+=128){
      float v;
      if(i<256) v = sCtx[k][i];
      else if(i<512) v = sCn[k][i-256];
      else if(i<768) v = sHn[k][i-512];
      else v = sX[k][i-768];
      p += v*wp[i];
    }
    sRed[t] = p; __syncthreads();
    for(int o=64;o>0;o>>=1){ if(uu<o) sRed[t]+=sRed[t+o]; __syncthreads(); }
    if(uu==0) pgenW[b*4+k] = sigf(sRed[t] + bp[0]);
  }
  __syncthreads();
  // out1: thread (h2,u) does beams h2, h2+2 (Wo1 load shared)
  {
    float a0 = bo1[u], a1 = bo1[u];
    #pragma unroll 4
    for(int i=0;i<HH;++i){
      float w = Wo1[i*HH + u];
      a0 += sHn[h2][i]*w; a1 += sHn[h2+2][i]*w;
    }
    #pragma unroll 4
    for(int i=0;i<HH;++i){
      float w = Wo1[(HH+i)*HH + u];
      a0 += sCtx[h2][i]*w; a1 += sCtx[h2+2][i]*w;
    }
    out1W[(size_t)(b*4+h2)*HH + u] = a0;
    out1W[(size_t)(b*4+h2+2)*HH + u] = a1;
  }
}

// ---------------- vocab GEMM: sumexp + chunk argmax (32 beams/block, XCD-swizzled) ----------------
// grid (NCHP=200, 8): linear id = c + 200*g  =>  id%8 = c%8  => all 8 beam-groups of a chunk
// land on the same XCD (round-robin heuristic), sharing its L2 for the chunk's 256 KB.
__global__ __launch_bounds__(256) void k_vocab2(
    const float* __restrict__ Wo2, const float* __restrict__ bo2,
    const float* __restrict__ out1W,
    float* __restrict__ sumexpW, float* __restrict__ cmaxW, int* __restrict__ cmaxIdW)
{
  int c = blockIdx.x;          // chunk (0..199, valid <196)
  if(c >= NCH) return;
  int g = blockIdx.y;          // beam group (8 groups of 32 beams)
  int bk0 = g*32;
  int t = threadIdx.x, lane = t&63, wv = t>>6;
  __shared__ __align__(16) float sT[32*HH];    // 32 KB
  for(int i=t; i<32*HH/4; i+=256)
    ((float4*)sT)[i] = ((const float4*)(out1W + (size_t)bk0*HH))[i];
  __syncthreads();

  const int vbase = c*VCH + lane*4;
  float acc[8][4];
  #pragma unroll
  for(int m=0;m<8;++m){
    #pragma unroll
    for(int j=0;j<4;++j) acc[m][j]=0.f;
  }
  const float* sTw = sT + wv*8*HH;
  const bool full = (c*VCH + VCH <= VV);
  if(full){
    for(int h=0; h<HH; h+=4){
      float4 w0 = *(const float4*)(Wo2 + (size_t)(h+0)*VV + vbase);
      float4 w1 = *(const float4*)(Wo2 + (size_t)(h+1)*VV + vbase);
      float4 w2 = *(const float4*)(Wo2 + (size_t)(h+2)*VV + vbase);
      float4 w3 = *(const float4*)(Wo2 + (size_t)(h+3)*VV + vbase);
      #pragma unroll
      for(int m=0;m<8;++m){
        float4 o = *(const float4*)(sTw + m*HH + h);
        acc[m][0] += w0.x*o.x + w1.x*o.y + w2.x*o.z + w3.x*o.w;
        acc[m][1] += w0.y*o.x + w1.y*o.y + w2.y*o.z + w3.y*o.w;
        acc[m][2] += w0.z*o.x + w1.z*o.y + w2.z*o.z + w3.z*o.w;
        acc[m][3] += w0.w*o.x + w1.w*o.y + w2.w*o.z + w3.w*o.w;
      }
    }
  } else {
    for(int h=0; h<HH; ++h){
      float wv4[4];
      #pragma unroll
      for(int j=0;j<4;++j){ int v = vbase+j; wv4[j] = (v<VV)? Wo2[(size_t)h*VV + v] : 0.f; }
      #pragma unroll
      for(int m=0;m<8;++m){
        float o = sTw[m*HH + h];
        #pragma unroll
        for(int j=0;j<4;++j) acc[m][j] += wv4[j]*o;
      }
    }
  }

  float lsum[8]; float lmax[8]; int lid[8];
  #pragma unroll
  for(int m=0;m<8;++m){ lsum[m]=0.f; lmax[m]=-INFINITY; lid[m]=-1; }
  #pragma unroll
  for(int j=0;j<4;++j){
    int v = vbase + j;
    if(v < VV){
      float bb2 = bo2[v];
      #pragma unroll
      for(int m=0;m<8;++m){
        float lg = acc[m][j] + bb2;
        lsum[m] += expf(lg);
        if(lg > lmax[m]){ lmax[m]=lg; lid[m]=v; }
      }
    }
  }
  #pragma unroll
  for(int m=0;m<8;++m){
    float s2 = lsum[m]; float mx = lmax[m]; int id = lid[m];
    #pragma unroll
    for(int o=1;o<64;o<<=1){
      s2 += __shfl_xor(s2, o, 64);
      float mx2 = __shfl_xor(mx, o, 64);
      int   id2 = __shfl_xor(id, o, 64);
      if(mx2 > mx || (mx2 == mx && (unsigned)id2 < (unsigned)id)){ mx = mx2; id = id2; }
    }
    if(lane == 0){
      int beam = bk0 + wv*8 + m;
      sumexpW[(size_t)beam*NCH + c] = s2;
      cmaxW  [(size_t)beam*NCH + c] = mx;
      cmaxIdW[(size_t)beam*NCH + c] = id;
    }
  }
}

// ---------------- fused copy-logits + candidate scoring + top-4 + state update ----------------
__global__ __launch_bounds__(256) void k_select(
    int tstep,
    const int* __restrict__ ids, const float* __restrict__ attnW, const float* __restrict__ pgenW,
    const float* __restrict__ sumexpW, const float* __restrict__ cmaxW, const int* __restrict__ cmaxIdW,
    const float* __restrict__ tmpW, const float* __restrict__ tmpB, const float* __restrict__ out1W,
    const int* __restrict__ nexts, const int* __restrict__ firstS, const unsigned* __restrict__ bmC,
    const float* __restrict__ hN, const float* __restrict__ cN, const float* __restrict__ ctxN,
    float* __restrict__ hS, float* __restrict__ cS, float* __restrict__ ctxS,
    float* __restrict__ logp, int* __restrict__ tokS, int* __restrict__ tokens,
    float* __restrict__ dout)
{
  int b = blockIdx.x, t = threadIdx.x, lane = t & 63, wv = t >> 6;
  __shared__ int   sIds[SS];
  __shared__ int   sNext[SS];
  __shared__ int   sFirst[SS];
  __shared__ unsigned sBm[NBMW];
  __shared__ float sAttn[4][SS];
  __shared__ float sLit[4][SS];
  __shared__ __align__(16) float sO[4*HH];
  __shared__ float sVal[4][NSLOT];
  __shared__ int   sCid[4][NSLOT];
  __shared__ float sLse[4], sPg[4], sLp[4];
  __shared__ float wredV[4]; __shared__ int wredK[4]; __shared__ int wredT[4];
  __shared__ int sTokOld[4][NSTEPS];

  for(int i=t;i<SS;i+=256){
    sIds[i]   = ids[(size_t)b*SS + i];
    sNext[i]  = nexts[(size_t)b*SS + i];
    sFirst[i] = firstS[(size_t)b*SS + i];
  }
  for(int i=t;i<NBMW;i+=256) sBm[i] = bmC[(size_t)b*NBMW + i];
  for(int i=t;i<4*SS;i+=256){ int k=i/SS, s=i-k*SS; sAttn[k][s] = attnW[(size_t)(b*4+k)*SS + s]; }
  for(int i=t;i<4*HH/4;i+=256)
    ((float4*)sO)[i] = ((const float4*)(out1W + (size_t)b*4*HH))[i];
  if(t<128){ int k=t>>5, u=t&31; sTokOld[k][u] = tokens[(size_t)(b*4+k)*NSTEPS + u]; }
  __syncthreads();
  // copy-logit dots: lit[k][s] = out1[b,k] . tmpW[b,s] + tmpB[b,s]
  {
    float4 o0 = ((const float4*)(sO + 0*HH))[lane];
    float4 o1 = ((const float4*)(sO + 1*HH))[lane];
    float4 o2 = ((const float4*)(sO + 2*HH))[lane];
    float4 o3 = ((const float4*)(sO + 3*HH))[lane];
    int s0 = wv*100;
    for(int sg=0; sg<100; sg+=4){
      float4 tw0 = ((const float4*)(tmpW + ((size_t)b*SS + s0+sg+0)*HH))[lane];
      float4 tw1 = ((const float4*)(tmpW + ((size_t)b*SS + s0+sg+1)*HH))[lane];
      float4 tw2 = ((const float4*)(tmpW + ((size_t)b*SS + s0+sg+2)*HH))[lane];
      float4 tw3 = ((const float4*)(tmpW + ((size_t)b*SS + s0+sg+3)*HH))[lane];
      #pragma unroll
      for(int q=0;q<4;++q){
        float4 tw = (q==0)?tw0:(q==1)?tw1:(q==2)?tw2:tw3;
        float p0 = tw.x*o0.x + tw.y*o0.y + tw.z*o0.z + tw.w*o0.w;
        float p1 = tw.x*o1.x + tw.y*o1.y + tw.z*o1.z + tw.w*o1.w;
        float p2 = tw.x*o2.x + tw.y*o2.y + tw.z*o2.z + tw.w*o2.w;
        float p3 = tw.x*o3.x + tw.y*o3.y + tw.z*o3.z + tw.w*o3.w;
        #pragma unroll
        for(int o=1;o<64;o<<=1){
          p0 += __shfl_xor(p0,o,64); p1 += __shfl_xor(p1,o,64);
          p2 += __shfl_xor(p2,o,64); p3 += __shfl_xor(p3,o,64);
        }
        if(lane==0){
          int s = s0+sg+q;
          float bb = tmpB[(size_t)b*SS + s];
          sLit[0][s] = p0 + bb; sLit[1][s] = p1 + bb;
          sLit[2][s] = p2 + bb; sLit[3][s] = p3 + bb;
        }
      }
    }
  }
  // lse / pgen / logp per beam
  {
    int beam = b*4 + wv;
    float p = 0.f;
    for(int cc=lane; cc<NCH; cc+=64) p += sumexpW[(size_t)beam*NCH + cc];
    #pragma unroll
    for(int o=1;o<64;o<<=1) p += __shfl_xor(p, o, 64);
    if(lane==0){ sLse[wv] = logf(p); sPg[wv] = pgenW[beam]; sLp[wv] = logp[beam]; }
  }
  __syncthreads();
  // copy candidates
  for(int i=t; i<4*SS; i+=256){
    int k=i/SS, s=i-k*SS;
    int id = sIds[s];
    float val = -INFINITY;
    if(sFirst[s]){
      float as = sAttn[k][s];
      int s2 = sNext[s];
      while(s2 >= 0){ as += sAttn[k][s2]; s2 = sNext[s2]; }
      float vp = 0.f;
      if(id < VV) vp = expf(sLit[k][s] - sLse[k]);
      float pg = sPg[k];
      val = sLp[k] + logf(pg*vp + (1.f-pg)*as + 1e-10f);
    }
    sVal[k][s] = val; sCid[k][s] = id;
  }
  // vocab safety-net candidates
  for(int i=t; i<4*NCH; i+=256){
    int k=i/NCH, cc=i-k*NCH;
    int beam = b*4 + k;
    int id = cmaxIdW[(size_t)beam*NCH + cc];
    float val = -INFINITY;
    if(id >= 0){
      bool member = (sBm[id>>5] >> (id&31)) & 1u;
      if(!member){
        float pg = sPg[k];
        val = sLp[k] + logf(pg*expf(cmaxW[(size_t)beam*NCH + cc] - sLse[k]) + 1e-10f);
      }
    }
    sVal[k][SS+cc] = val; sCid[k][SS+cc] = id;
  }
  __syncthreads();
  // per-thread local top-4 over strided slots
  float lv[4] = {-INFINITY,-INFINITY,-INFINITY,-INFINITY};
  int   lk[4] = {INT_MAX,INT_MAX,INT_MAX,INT_MAX};
  for(int i=t; i<4*NSLOT; i+=256){
    int k = i/NSLOT, sl = i - k*NSLOT;
    float v = sVal[k][sl];
    if(!(v > -INFINITY)) continue;
    int key = k*VEXTT + sCid[k][sl];
    if(betterf(v, key, lv[3], lk[3])){
      lv[3]=v; lk[3]=key;
      #pragma unroll
      for(int j=3;j>0;--j){
        if(betterf(lv[j],lk[j],lv[j-1],lk[j-1])){
          float tv=lv[j]; lv[j]=lv[j-1]; lv[j-1]=tv;
          int tk2=lk[j]; lk[j]=lk[j-1]; lk[j-1]=tk2;
        }
      }
    }
  }
  // 4 selection rounds
  int hp = 0;
  float selv[4]; int selk[4], seli[4];
  for(int r=0;r<4;++r){
    float hv = (hp<4) ? lv[hp] : -INFINITY;
    int   hk = (hp<4) ? lk[hp] : INT_MAX;
    float bv = hv; int bk2 = hk; int btid = t;
    #pragma unroll
    for(int o=1;o<64;o<<=1){
      float ov = __shfl_xor(bv,o,64);
      int   ok = __shfl_xor(bk2,o,64);
      int   ot = __shfl_xor(btid,o,64);
      if(betterf(ov,ok,bv,bk2)){ bv=ov; bk2=ok; btid=ot; }
    }
    if(lane==0){ wredV[wv]=bv; wredK[wv]=bk2; wredT[wv]=btid; }
    __syncthreads();
    float gv = wredV[0]; int gk = wredK[0], gt = wredT[0];
    #pragma unroll
    for(int w2=1;w2<4;++w2)
      if(betterf(wredV[w2],wredK[w2],gv,gk)){ gv=wredV[w2]; gk=wredK[w2]; gt=wredT[w2]; }
    if(t == gt) hp++;
    int kk = gk / VEXTT;
    selv[r] = gv; selk[r] = kk; seli[r] = gk - kk*VEXTT;
    __syncthreads();
  }
  // state update via backpointers
  for(int j=0;j<4;++j){
    int kj = selk[j];
    hS  [(size_t)(b*4+j)*HH + t] = hN  [(size_t)(b*4+kj)*HH + t];
    cS  [(size_t)(b*4+j)*HH + t] = cN  [(size_t)(b*4+kj)*HH + t];
    ctxS[(size_t)(b*4+j)*HH + t] = ctxN[(size_t)(b*4+kj)*HH + t];
  }
  if(t<4){ logp[b*4+t] = selv[t]; tokS[b*4+t] = seli[t]; }
  if(t<128){
    int j=t>>5, u=t&31;
    int nv = (u==tstep) ? seli[j] : sTokOld[selk[j]][u];
    tokens[(size_t)(b*4+j)*NSTEPS + u] = nv;
    if(tstep == NSTEPS-1) dout[(size_t)(b*4+j)*NSTEPS + u] = (float)nv;
  }
  if(tstep == NSTEPS-1 && t<4) dout[(size_t)BB*4*NSTEPS + b*4 + t] = selv[t];
}

extern "C" void kernel_launch(void* const* d_in, const int* in_sizes, int n_in,
                              void* d_out, int out_size, void* d_ws, size_t ws_size,
                              hipStream_t stream) {
  const float* enc  = (const float*)d_in[0];
  const int*   ids  = (const int*)  d_in[2];
  const float* h0   = (const float*)d_in[3];
  const float* c0   = (const float*)d_in[4];
  const float* embw = (const float*)d_in[5];
  const float* Win  = (const float*)d_in[6];
  const float* bin  = (const float*)d_in[7];
  const float* Wl   = (const float*)d_in[8];
  const float* bl   = (const float*)d_in[9];
  const float* Wenc = (const float*)d_in[10];
  const float* Wd   = (const float*)d_in[11];
  const float* ba   = (const float*)d_in[12];
  const float* va   = (const float*)d_in[13];
  const float* wp   = (const float*)d_in[14];
  const float* bp   = (const float*)d_in[15];
  const float* Wo1  = (const float*)d_in[16];
  const float* bo1  = (const float*)d_in[17];
  const float* Wo2  = (const float*)d_in[18];
  const float* bo2  = (const float*)d_in[19];

  char* w = (char*)d_ws;
  auto alloc = [&](size_t bytes)->void*{ void* p = (void*)w; w += (bytes + 255) & ~(size_t)255; return p; };
  float* ef     = (float*)alloc((size_t)BB*SS*HH*4);
  float* tmpW   = (float*)alloc((size_t)BB*SS*HH*4);
  float* tmpB   = (float*)alloc((size_t)BB*SS*4);
  int*   nextsW = (int*)  alloc((size_t)BB*SS*4);
  int*   firstW = (int*)  alloc((size_t)BB*SS*4);
  unsigned* bmC = (unsigned*)alloc((size_t)BB*NBMW*4);
  float* hS     = (float*)alloc((size_t)NBK*HH*4);
  float* cS     = (float*)alloc((size_t)NBK*HH*4);
  float* ctxS   = (float*)alloc((size_t)NBK*HH*4);
  float* logpW  = (float*)alloc((size_t)NBK*4);
  int*   tokW   = (int*)  alloc((size_t)NBK*4);
  int*   tokensW= (int*)  alloc((size_t)NBK*NSTEPS*4);
  float* hN     = (float*)alloc((size_t)NBK*HH*4);
  float* cN     = (float*)alloc((size_t)NBK*HH*4);
  float* ctxN   = (float*)alloc((size_t)NBK*HH*4);
  float* attnW  = (float*)alloc((size_t)NBK*SS*4);
  float* out1W  = (float*)alloc((size_t)NBK*HH*4);
  float* pgenW  = (float*)alloc((size_t)NBK*4);
  float* sumexpW= (float*)alloc((size_t)NBK*NCH*4);
  float* cmaxW  = (float*)alloc((size_t)NBK*NCH*4);
  int*   cmaxIdW= (int*)  alloc((size_t)NBK*NCH*4);
  float* dfW    = (float*)alloc((size_t)NBK*HH*4);
  float* xW     = (float*)alloc((size_t)NBK*EE*4);
  float* eWbuf  = (float*)alloc((size_t)NBK*SS*4);
  float* ctxP   = (float*)alloc((size_t)BB*4*4*HH*4);

  hipLaunchKernelGGL(k_init, dim3(NBK), dim3(HH), 0, stream, h0, c0, hS, cS, ctxS, logpW, tokW, tokensW);
  hipLaunchKernelGGL(k_encfeats, dim3(BB*(SS/TSR)), dim3(256), 0, stream, enc, Wenc, ef);
  hipLaunchKernelGGL(k_prep, dim3(BB), dim3(256), 0, stream, ids, nextsW, firstW, bmC);
  hipLaunchKernelGGL(k_gatherW, dim3(16, 100), dim3(256), 0, stream, Wo2, bo2, ids, tmpW, tmpB);

  for(int tstep=0; tstep<NSTEPS; ++tstep){
    hipLaunchKernelGGL(k_recur, dim3(NBK/4), dim3(256), 0, stream,
                       embw, Win, bin, Wl, bl, Wd, tokW, hS, cS, ctxS,
                       hN, cN, dfW, xW);
    hipLaunchKernelGGL(k_e, dim3(8, BB), dim3(256), 0, stream,
                       ba, va, ef, dfW, eWbuf);
    hipLaunchKernelGGL(k_ctxA, dim3(BB, 4), dim3(512), 0, stream,
                       enc, eWbuf, attnW, ctxP);
    hipLaunchKernelGGL(k_ctxB, dim3(BB), dim3(512), 0, stream,
                       wp, bp, Wo1, bo1, ctxP, cN, hN, xW,
                       ctxN, out1W, pgenW);
    hipLaunchKernelGGL(k_vocab2, dim3(NCHP, 8), dim3(256), 0, stream,
                       Wo2, bo2, out1W, sumexpW, cmaxW, cmaxIdW);
    hipLaunchKernelGGL(k_select, dim3(BB), dim3(256), 0, stream, tstep,
                       ids, attnW, pgenW, sumexpW, cmaxW, cmaxIdW,
                       tmpW, tmpB, out1W,
                       nextsW, firstW, bmC,
                       hN, cN, ctxN, hS, cS, ctxS, logpW, tokW, tokensW,
                       (float*)d_out);
  }
}